// Round 9
// baseline (418.961 us; speedup 1.0000x reference)
//
#include <hip/hip_runtime.h>
#include <hip/hip_bf16.h>
#include <stdint.h>

// MLAAttention on MI355X (gfx950).
// B=4 T=4096 D=1024 H=16 M=64 Dh=64. All inputs f32 (mask int32), output f32.
// R9: gemm256 -> 8-phase counted-vmcnt schedule (T3+T4 on top of R8's T2 swizzle).
//     Iteration = 2 K-tiles; phase = {vmcnt(4)@ph0/ph4; lgkm0+barrier; ds_read
//     subtile || 1 half-tile stage; 16 MFMA setprio-wrapped}. Stage issued >=1
//     barrier after the region's last (completed) read; kt's 4 half-tiles land
//     >=4 phases before consumption with exactly 4 younger loads in flight.

#define DEV static __device__ __forceinline__

using short8 = __attribute__((ext_vector_type(8))) short;
using f32x4  = __attribute__((ext_vector_type(4))) float;

#define ZERO4 (f32x4){0.f, 0.f, 0.f, 0.f}

DEV float bf2f(unsigned short u) {
  union { unsigned int i; float f; } c; c.i = ((unsigned int)u) << 16; return c.f;
}
DEV unsigned short f2bf(float f) {
  __hip_bfloat16 h = __float2bfloat16(f);
  unsigned short u; __builtin_memcpy(&u, &h, 2); return u;
}
DEV f32x4 mfma16(short8 a, short8 b, f32x4 c) {
  return __builtin_amdgcn_mfma_f32_16x16x32_bf16(a, b, c, 0, 0, 0);
}
#define GLOAD_LDS16(G, L) __builtin_amdgcn_global_load_lds( \
    (const __attribute__((address_space(1))) void*)(G),     \
    (__attribute__((address_space(3))) void*)(L), 16, 0, 0)

// ---------------------------------------------------------------- convert
__global__ void cvt_bf16(const float* __restrict__ src,
                         __hip_bfloat16* __restrict__ dst, int n) {
  int i = (blockIdx.x * blockDim.x + threadIdx.x) * 4;
  if (i >= n) return;
  const float4 v = *(const float4*)(src + i);
  ushort4 o;
  o.x = f2bf(v.x); o.y = f2bf(v.y); o.z = f2bf(v.z); o.w = f2bf(v.w);
  *(ushort4*)(dst + i) = o;
}

// ---------------------------------------------------------------- GEMM 256x256
// C[M,N] = A[M,K] @ Bt[N,K]^T, bf16 in, f32 acc. 8 waves (2M x 4N).
// 8-phase K-loop over 2 K-tiles/iter; XOR-swizzled LDS (R8): element (row,
// chunk c) at LDS (row, c ^ (row&7)); staged linear + pre-swizzled source.
// MODE: 0 = f32 normal; 1 = bf16 normal; 2 = bf16 normal + bf16 transposed;
//       3 = bf16 transposed only.
// ROPE: rotary on acc before stores (pairs along n; t = m&4095, d = n&63).
// Transposed layout: Ct[((m>>12)*16 + (n>>6))*64 + (n&63)][t = m&4095]  (bf16)
template<int MODE, int ROPE>
__global__ __launch_bounds__(512, 2)
void gemm256(const __hip_bfloat16* __restrict__ A,
             const __hip_bfloat16* __restrict__ Bt,
             void* __restrict__ Cout, __hip_bfloat16* __restrict__ Ct,
             const float* __restrict__ cosT, const float* __restrict__ sinT,
             int M, int N, int K) {
  __shared__ __hip_bfloat16 As[2][256 * 64];
  __shared__ __hip_bfloat16 Bs[2][256 * 64];
  const int tid = threadIdx.x;
  const int w = tid >> 6, l = tid & 63;
  const int lr = l & 15, lg = l >> 4;
  const int rowA0 = blockIdx.x * 256;
  const int colB0 = blockIdx.y * 256;
  const int srow = w * 8 + (l >> 3);                 // staging row (row&7 = l>>3)
  const int skk  = (((l & 7) ^ (l >> 3)) * 8);       // pre-swizzled source k-chunk
  const __hip_bfloat16* Ab = A  + (size_t)(rowA0 + srow) * K + skk;
  const __hip_bfloat16* Bb = Bt + (size_t)(colB0 + srow) * K + skk;
  f32x4 acc[8][4];
#pragma unroll
  for (int i = 0; i < 8; ++i)
#pragma unroll
    for (int j = 0; j < 4; ++j) acc[i][j] = ZERO4;
  const int wr = (w >> 2) * 128;          // wave M-offset (0 or 128)
  const int wc = (w & 3) * 64;            // wave N-offset (0,64,128,192)
  const int NT = K >> 6;                  // 64-wide K-tiles (16 here)
  const int NI = NT >> 1;                 // iterations (2 K-tiles each)

  // stage one half-tile (128 rows x 64 k) of A or B for K-tile kt into buf kt&1
#define STAGE_A(kt, h)                                                           \
  if ((kt) < NT) {                                                               \
    const size_t go = (size_t)((h) * 128) * K + (size_t)(kt) * 64;               \
    GLOAD_LDS16(Ab + go,                &As[(kt) & 1][((h) * 128 + w * 8) * 64]); \
    GLOAD_LDS16(Ab + go + (size_t)64 * K, &As[(kt) & 1][((h) * 128 + 64 + w * 8) * 64]); \
  }
#define STAGE_B(kt, h)                                                           \
  if ((kt) < NT) {                                                               \
    const size_t go = (size_t)((h) * 128) * K + (size_t)(kt) * 64;               \
    GLOAD_LDS16(Bb + go,                &Bs[(kt) & 1][((h) * 128 + w * 8) * 64]); \
    GLOAD_LDS16(Bb + go + (size_t)64 * K, &Bs[(kt) & 1][((h) * 128 + 64 + w * 8) * 64]); \
  }
  // read this wave's fragments for k-half s from buffer buf (swizzled chunk)
#define READ_FRAGS(buf, s, FA, FB)                                               \
  {                                                                              \
    _Pragma("unroll")                                                            \
    for (int i = 0; i < 8; ++i)                                                  \
      FA[i] = *(const short8*)&As[buf][(wr + i * 16 + lr) * 64 +                 \
                                       ((((s) * 4 + lg) ^ (lr & 7)) * 8)];       \
    _Pragma("unroll")                                                            \
    for (int j = 0; j < 4; ++j)                                                  \
      FB[j] = *(const short8*)&Bs[buf][(wc + j * 16 + lr) * 64 +                 \
                                       ((((s) * 4 + lg) ^ (lr & 7)) * 8)];       \
  }
#define MM(FA, FB, j0)                                                           \
  {                                                                              \
    __builtin_amdgcn_s_setprio(1);                                               \
    _Pragma("unroll")                                                            \
    for (int i = 0; i < 8; ++i) {                                                \
      acc[i][j0] = mfma16(FA[i], FB[j0], acc[i][j0]);                            \
      acc[i][j0 + 1] = mfma16(FA[i], FB[j0 + 1], acc[i][j0 + 1]);                \
    }                                                                            \
    __builtin_amdgcn_s_setprio(0);                                               \
  }
  // phase boundary: own reads complete, then block-wide barrier
#define PH_SYNC                                                                  \
  asm volatile("s_waitcnt lgkmcnt(0)" ::: "memory");                             \
  __builtin_amdgcn_s_barrier();                                                  \
  asm volatile("" ::: "memory");

  // prologue: kt0 fully, kt1 A-halves  (12 loads/thread)
  STAGE_A(0, 0); STAGE_A(0, 1); STAGE_B(0, 0); STAGE_B(0, 1);
  STAGE_A(1, 0); STAGE_A(1, 1);

  for (int it = 0; it < NI; ++it) {
    const int k0 = 2 * it, k1 = 2 * it + 1;
    short8 fa0[8], fb0[4], fa1[8], fb1[4];
    // ph0: need k0 (buf0); 4 younger loads (k1 A-halves) stay in flight
    asm volatile("s_waitcnt vmcnt(4)" ::: "memory");
    PH_SYNC;
    READ_FRAGS(0, 0, fa0, fb0);
    STAGE_B(k1, 0);
    MM(fa0, fb0, 0);
    // ph1
    PH_SYNC;
    READ_FRAGS(0, 1, fa1, fb1);
    STAGE_B(k1, 1);
    MM(fa0, fb0, 2);
    // ph2  (buf0 reads done -> safe to restage buf0 with k0+2)
    PH_SYNC;
    STAGE_A(k0 + 2, 0);
    MM(fa1, fb1, 0);
    // ph3
    PH_SYNC;
    STAGE_A(k0 + 2, 1);
    MM(fa1, fb1, 2);
    // ph4: need k1 (buf1); younger loads = k0+2 A-halves (4), or 0 on last iter
    if (it + 1 < NI) { asm volatile("s_waitcnt vmcnt(4)" ::: "memory"); }
    else             { asm volatile("s_waitcnt vmcnt(0)" ::: "memory"); }
    PH_SYNC;
    READ_FRAGS(1, 0, fa0, fb0);
    STAGE_B(k0 + 2, 0);
    MM(fa0, fb0, 0);
    // ph5
    PH_SYNC;
    READ_FRAGS(1, 1, fa1, fb1);
    STAGE_B(k0 + 2, 1);
    MM(fa0, fb0, 2);
    // ph6  (buf1 reads done -> safe to restage buf1 with k0+3)
    PH_SYNC;
    STAGE_A(k0 + 3, 0);
    MM(fa1, fb1, 0);
    // ph7
    PH_SYNC;
    STAGE_A(k0 + 3, 1);
    MM(fa1, fb1, 2);
  }
#undef STAGE_A
#undef STAGE_B
#undef READ_FRAGS
#undef MM
#undef PH_SYNC

  const int r0 = rowA0 + wr + lg * 4;     // global row (m) base, +i*16+r
  const int c0 = colB0 + wc + lr;         // global col (n), +j*16
  if (ROPE) {
#pragma unroll
    for (int i = 0; i < 8; ++i)
#pragma unroll
      for (int j = 0; j < 4; ++j)
#pragma unroll
        for (int r = 0; r < 4; ++r) {
          const int m = r0 + i * 16 + r;
          const int n = c0 + j * 16;
          const int t = m & 4095, d = n & 63;
          const float c = cosT[t * 64 + d];
          const float s = sinT[t * 64 + d];
          const float v = acc[i][j][r];
          const float other = __shfl_xor(v, 1, 64);
          acc[i][j][r] = v * c + ((n & 1) ? other : -other) * s;
        }
  }
  if (MODE <= 2) {
#pragma unroll
    for (int i = 0; i < 8; ++i)
#pragma unroll
      for (int j = 0; j < 4; ++j)
#pragma unroll
        for (int r = 0; r < 4; ++r) {
          const size_t idx = (size_t)(r0 + i * 16 + r) * N + (c0 + j * 16);
          if (MODE == 0) ((float*)Cout)[idx] = acc[i][j][r];
          else ((__hip_bfloat16*)Cout)[idx] = __float2bfloat16(acc[i][j][r]);
        }
  }
  if (MODE >= 2) {
#pragma unroll
    for (int i = 0; i < 8; ++i)
#pragma unroll
      for (int j = 0; j < 4; ++j) {
        const int m0 = r0 + i * 16;           // 4 contiguous t per lane
        const int n  = c0 + j * 16;
        const size_t row = (size_t)(((m0 >> 12) * 16 + (n >> 6)) * 64 + (n & 63));
        ushort4 pk;
        pk.x = f2bf(acc[i][j][0]); pk.y = f2bf(acc[i][j][1]);
        pk.z = f2bf(acc[i][j][2]); pk.w = f2bf(acc[i][j][3]);
        *(ushort4*)&Ct[row * 4096 + (m0 & 4095)] = pk;
      }
  }
}

// ---------------------------------------------------------------- stage1 logits (MFMA)
// S[bh][m][t] = 0.125 * sum_d latent[h][m][d]*K[b][t][h][d]  (bf16 store; -inf if masked)
// Fused online per-m (max,sum) partials: pmax/psum[(bh*8+chunk)*4 + wave][m].
__global__ __launch_bounds__(256)
void stage1_logits(const __hip_bfloat16* __restrict__ kmat,  // [B,T,H,64] (roped)
                   const float* __restrict__ latent,          // [H,64,64] f32
                   const int* __restrict__ mask,               // [B*T]
                   __hip_bfloat16* __restrict__ S,             // [bh][64][4096]
                   float* __restrict__ pmax, float* __restrict__ psum) {
  const int bh = blockIdx.x, chunk = blockIdx.y;
  const int b = bh >> 4, h = bh & 15;
  const int tid = threadIdx.x, w = tid >> 6, l = tid & 63;
  const int lr = l & 15, lg = l >> 4;
  short8 la[4][2];
#pragma unroll
  for (int n = 0; n < 4; ++n)
#pragma unroll
    for (int s = 0; s < 2; ++s) {
      const float* lp = &latent[((size_t)h * 64 + n * 16 + lr) * 64 + s * 32 + lg * 8];
      short8 f;
#pragma unroll
      for (int j = 0; j < 8; ++j) f[j] = (short)f2bf(lp[j]);
      la[n][s] = f;
    }
  float mx[16], sm[16];
#pragma unroll
  for (int i = 0; i < 16; ++i) { mx[i] = -3.0e38f; sm[i] = 0.f; }
  for (int tile = 0; tile < 8; ++tile) {
    const int t = chunk * 512 + tile * 64 + w * 16 + lr;
    const __hip_bfloat16* kp = &kmat[((size_t)(b * 4096 + t) * 16 + h) * 64 + lg * 8];
    const short8 kb0 = *(const short8*)kp;
    const short8 kb1 = *(const short8*)(kp + 32);
    const bool live = (mask[b * 4096 + t] != 0);
    f32x4 acc[4];
#pragma unroll
    for (int n = 0; n < 4; ++n) {
      acc[n] = ZERO4;
      acc[n] = mfma16(la[n][0], kb0, acc[n]);
      acc[n] = mfma16(la[n][1], kb1, acc[n]);
    }
#pragma unroll
    for (int n = 0; n < 4; ++n)
#pragma unroll
      for (int r = 0; r < 4; ++r) {
        const float v = acc[n][r] * 0.125f;
        const int m = n * 16 + lg * 4 + r;
        unsigned short sv = live ? f2bf(v) : (unsigned short)0xFF80;  // -inf
        ((unsigned short*)S)[((size_t)bh * 64 + m) * 4096 + t] = sv;
        if (live) {
          const int idx = n * 4 + r;
          const float nm = fmaxf(mx[idx], v);
          sm[idx] = sm[idx] * __expf(mx[idx] - nm) + __expf(v - nm);
          mx[idx] = nm;
        }
      }
  }
#pragma unroll
  for (int o = 1; o < 16; o <<= 1)
#pragma unroll
    for (int i = 0; i < 16; ++i) {
      const float omx = __shfl_xor(mx[i], o, 64);
      const float osm = __shfl_xor(sm[i], o, 64);
      const float nm = fmaxf(mx[i], omx);
      sm[i] = sm[i] * __expf(mx[i] - nm) + osm * __expf(omx - nm);
      mx[i] = nm;
    }
  if (lr == 0) {
    const size_t pb = ((size_t)(bh * 8 + chunk) * 4 + w) * 64;
#pragma unroll
    for (int n = 0; n < 4; ++n)
#pragma unroll
      for (int r = 0; r < 4; ++r) {
        const int m = n * 16 + lg * 4 + r;
        pmax[pb + m] = mx[n * 4 + r];
        psum[pb + m] = sm[n * 4 + r];
      }
  }
}

// combine 32 partials per (bh,m)
__global__ void stage1_reduce(const float* __restrict__ pmax,
                              const float* __restrict__ psum,
                              float* __restrict__ cmax, float* __restrict__ cinv) {
  const int i = blockIdx.x * 256 + threadIdx.x;
  if (i >= 4096) return;
  const int bh = i >> 6, m = i & 63;
  float mx = -3.0e38f;
#pragma unroll
  for (int c = 0; c < 32; ++c)
    mx = fmaxf(mx, pmax[((size_t)bh * 32 + c) * 64 + m]);
  float sm = 0.f;
#pragma unroll
  for (int c = 0; c < 32; ++c)
    sm += psum[((size_t)bh * 32 + c) * 64 + m] *
          __expf(pmax[((size_t)bh * 32 + c) * 64 + m] - mx);
  cmax[i] = mx;
  cinv[i] = 1.f / sm;
}

// ---------------------------------------------------------------- latent GEMM v5
// Direct-from-global register-fragment MFMA reduction with FUSED softmax-exp:
// fp = bf16(exp(S - cmax)*cinv) computed in-register from raw logits S.
// k_lat_part[m,d] = sum_t P[m,t]*kT[d,t]; v_latT_part[d,m] = sum_t vT[d,t]*P[m,t].
__global__ __launch_bounds__(256)
void latgemm5(const __hip_bfloat16* __restrict__ S,   // logits [bh][64][4096]
              const __hip_bfloat16* __restrict__ kT,
              const __hip_bfloat16* __restrict__ vT,
              const float* __restrict__ cmax, const float* __restrict__ cinv,
              float* __restrict__ partials) {   // [slice][bh][8192]
  const int bh = blockIdx.x;
  const int tid = threadIdx.x, w = tid >> 6, l = tid & 63;
  const int slice = blockIdx.y * 4 + w;
  const int lr = l & 15;            // frag row
  const int lk = (l >> 4) * 8;      // frag k-offset
  const size_t base = (size_t)bh * 64 * 4096;
  float cm[4], ci[4];
#pragma unroll
  for (int i = 0; i < 4; ++i) {
    cm[i] = cmax[bh * 64 + i * 16 + lr];
    ci[i] = cinv[bh * 64 + i * 16 + lr];
  }
  f32x4 ak[4][4], av[4][4];
#pragma unroll
  for (int i = 0; i < 4; ++i)
#pragma unroll
    for (int j = 0; j < 4; ++j) { ak[i][j] = ZERO4; av[i][j] = ZERO4; }
  for (int ks = 0; ks < 8; ++ks) {
    const int t = slice * 256 + ks * 32 + lk;
    short8 fp[4], fk[4], fv[4];
#pragma unroll
    for (int i = 0; i < 4; ++i) {
      const size_t ro = base + (size_t)(i * 16 + lr) * 4096 + t;
      const short8 sv = *(const short8*)&S[ro];
      short8 p;
#pragma unroll
      for (int j = 0; j < 8; ++j)
        p[j] = (short)f2bf(__expf(bf2f((unsigned short)sv[j]) - cm[i]) * ci[i]);
      fp[i] = p;
      fk[i] = *(const short8*)&kT[ro];
      fv[i] = *(const short8*)&vT[ro];
    }
#pragma unroll
    for (int i = 0; i < 4; ++i)
#pragma unroll
      for (int j = 0; j < 4; ++j) {
        ak[i][j] = mfma16(fp[i], fk[j], ak[i][j]);   // C[m][d]
        av[i][j] = mfma16(fv[i], fp[j], av[i][j]);   // C[d][m]
      }
  }
  float* pk = partials + ((size_t)(slice * 64 + bh)) * 8192;
#pragma unroll
  for (int i = 0; i < 4; ++i)
#pragma unroll
    for (int j = 0; j < 4; ++j)
#pragma unroll
      for (int r = 0; r < 4; ++r) {
        const int row = i * 16 + 4 * (l >> 4) + r;
        const int col = j * 16 + lr;
        pk[(size_t)row * 64 + col]        = ak[i][j][r];
        pk[4096 + (size_t)row * 64 + col] = av[i][j][r];
      }
}

// Sum 16 slice-partials -> bf16 k_lat [bh][m][d] and v_latT [bh][d][m]
__global__ void latreduce(const float* __restrict__ partials,
                          __hip_bfloat16* __restrict__ k_lat,
                          __hip_bfloat16* __restrict__ v_latT) {
  const int i = blockIdx.x * 256 + threadIdx.x;   // 524288
  const int bh = i >> 13, off = i & 8191;
  float sm = 0.f;
#pragma unroll
  for (int c = 0; c < 16; ++c)
    sm += partials[((size_t)(c * 64 + bh)) * 8192 + off];
  if (off < 4096) k_lat[(size_t)bh * 4096 + off] = __float2bfloat16(sm);
  else            v_latT[(size_t)bh * 4096 + (off - 4096)] = __float2bfloat16(sm);
}

// ---------------------------------------------------------------- stage2 fused
__global__ __launch_bounds__(256)
void stage2_attn(const __hip_bfloat16* __restrict__ q,
                 const __hip_bfloat16* __restrict__ k_lat,
                 const __hip_bfloat16* __restrict__ v_latT,
                 __hip_bfloat16* __restrict__ attn) {
  __shared__ unsigned short Pl[4][16][64];
  const int bid = blockIdx.x;
  const int bh = bid >> 6, tt = (bid & 63) * 64;
  const int b = bh >> 4, h = bh & 15;
  const int tid = threadIdx.x, w = tid >> 6, l = tid & 63;
  const size_t qoff = ((size_t)(b * 4096 + tt + w * 16 + (l & 15)) * 16 + h) * 64;
  const short8 a0 = *(const short8*)&q[qoff + (l >> 4) * 8];
  const short8 a1 = *(const short8*)&q[qoff + 32 + (l >> 4) * 8];
  f32x4 att[4];
#pragma unroll
  for (int n = 0; n < 4; ++n) att[n] = ZERO4;
#pragma unroll
  for (int n = 0; n < 4; ++n) {
    const __hip_bfloat16* kl = &k_lat[((size_t)bh * 64 + n * 16 + (l & 15)) * 64];
    const short8 b0 = *(const short8*)&kl[(l >> 4) * 8];
    const short8 b1 = *(const short8*)&kl[32 + (l >> 4) * 8];
    att[n] = mfma16(a0, b0, att[n]);
    att[n] = mfma16(a1, b1, att[n]);
  }
  float p[4][4];
#pragma unroll
  for (int r = 0; r < 4; ++r) {
    const float v0 = att[0][r] * 0.125f, v1 = att[1][r] * 0.125f;
    const float v2 = att[2][r] * 0.125f, v3 = att[3][r] * 0.125f;
    float mxv = fmaxf(fmaxf(v0, v1), fmaxf(v2, v3));
#pragma unroll
    for (int o = 1; o < 16; o <<= 1) mxv = fmaxf(mxv, __shfl_xor(mxv, o, 64));
    const float e0 = __expf(v0 - mxv), e1 = __expf(v1 - mxv);
    const float e2 = __expf(v2 - mxv), e3 = __expf(v3 - mxv);
    float sum = e0 + e1 + e2 + e3;
#pragma unroll
    for (int o = 1; o < 16; o <<= 1) sum += __shfl_xor(sum, o, 64);
    const float inv = 1.f / sum;
    p[0][r] = e0 * inv; p[1][r] = e1 * inv; p[2][r] = e2 * inv; p[3][r] = e3 * inv;
  }
#pragma unroll
  for (int n = 0; n < 4; ++n)
#pragma unroll
    for (int r = 0; r < 4; ++r) {
      const int row = 4 * (l >> 4) + r;
      const int col = n * 16 + (l & 15);
      Pl[w][row][col ^ ((row & 7) << 3)] = f2bf(p[n][r]);
    }
  __syncthreads();
  const int arow = l & 15;
  const short8 pa0 = *(const short8*)&Pl[w][arow][(((l >> 4) + 0) ^ (arow & 7)) * 8];
  const short8 pa1 = *(const short8*)&Pl[w][arow][(((l >> 4) + 4) ^ (arow & 7)) * 8];
  f32x4 ov[4];
#pragma unroll
  for (int n = 0; n < 4; ++n) ov[n] = ZERO4;
#pragma unroll
  for (int n = 0; n < 4; ++n) {
    const __hip_bfloat16* vt = &v_latT[((size_t)bh * 64 + n * 16 + (l & 15)) * 64];
    const short8 b0 = *(const short8*)&vt[(l >> 4) * 8];
    const short8 b1 = *(const short8*)&vt[32 + (l >> 4) * 8];
    ov[n] = mfma16(pa0, b0, ov[n]);
    ov[n] = mfma16(pa1, b1, ov[n]);
  }
#pragma unroll
  for (int n = 0; n < 4; ++n) {
    const int d = n * 16 + (l & 15);
#pragma unroll
    for (int r = 0; r < 4; ++r) {
      const int trow = tt + w * 16 + 4 * (l >> 4) + r;
      attn[((size_t)(b * 4096 + trow) * 16 + h) * 64 + d] = __float2bfloat16(ov[n][r]);
    }
  }
}

// ---------------------------------------------------------------- launch
extern "C" void kernel_launch(void* const* d_in, const int* in_sizes, int n_in,
                              void* d_out, int out_size, void* d_ws, size_t ws_size,
                              hipStream_t stream) {
  const float* x      = (const float*)d_in[0];
  const float* Wq     = (const float*)d_in[1];
  const float* Wk     = (const float*)d_in[2];
  const float* Wv     = (const float*)d_in[3];
  const float* Wo     = (const float*)d_in[4];
  const float* latent = (const float*)d_in[5];
  const float* cosT   = (const float*)d_in[6];
  const float* sinT   = (const float*)d_in[7];
  const int*   mask   = (const int*)d_in[8];

  char* ws = (char*)d_ws;
  __hip_bfloat16* xb = (__hip_bfloat16*)ws;                        // 33.5MB (reused as S)
  __hip_bfloat16* Wb = (__hip_bfloat16*)(ws + 33554432);           // 8.4MB
  __hip_bfloat16* qb = (__hip_bfloat16*)(ws + 41943040);           // 33.5MB (reused as attn)
  __hip_bfloat16* kb = (__hip_bfloat16*)(ws + 75497472);           // 33.5MB (reused as partials)
  __hip_bfloat16* kT = (__hip_bfloat16*)(ws + 109051904);          // 33.5MB [bh*64+d][t]
  __hip_bfloat16* vT = (__hip_bfloat16*)(ws + 142606336);          // 33.5MB
  char* tail = ws + 176160768;
  float* pmax = (float*)tail;                       // 131072 f
  float* psum = pmax + 131072;
  float* cmax = psum + 131072;                      // 4096 f
  float* cinv = cmax + 4096;
  __hip_bfloat16* k_lat  = (__hip_bfloat16*)(cinv + 4096);   // 262144 bf16
  __hip_bfloat16* v_latT = k_lat + 262144;

  __hip_bfloat16* S    = xb;                // xb dead after projection GEMMs
  __hip_bfloat16* attn = qb;                // qb dead after stage2 (in-place ok)
  float* partials = (float*)kb;             // kb dead after stage1_logits

  cvt_bf16<<<16384, 256, 0, stream>>>(x, xb, 16777216);
  cvt_bf16<<<1024, 256, 0, stream>>>(Wq, Wb + 0 * 1048576, 1048576);
  cvt_bf16<<<1024, 256, 0, stream>>>(Wk, Wb + 1 * 1048576, 1048576);
  cvt_bf16<<<1024, 256, 0, stream>>>(Wv, Wb + 2 * 1048576, 1048576);
  cvt_bf16<<<1024, 256, 0, stream>>>(Wo, Wb + 3 * 1048576, 1048576);

  dim3 gg(64, 4);
  gemm256<1, 1><<<gg, 512, 0, stream>>>(xb, Wb + 0 * 1048576, qb, nullptr, cosT, sinT, 16384, 1024, 1024);
  gemm256<2, 1><<<gg, 512, 0, stream>>>(xb, Wb + 1 * 1048576, kb, kT, cosT, sinT, 16384, 1024, 1024);
  gemm256<3, 0><<<gg, 512, 0, stream>>>(xb, Wb + 2 * 1048576, nullptr, vT, nullptr, nullptr, 16384, 1024, 1024);

  dim3 sg(64, 8);
  stage1_logits<<<sg, 256, 0, stream>>>(kb, latent, mask, S, pmax, psum);
  stage1_reduce<<<16, 256, 0, stream>>>(pmax, psum, cmax, cinv);

  dim3 lg(64, 4);
  latgemm5<<<lg, 256, 0, stream>>>(S, kT, vT, cmax, cinv, partials);
  latreduce<<<2048, 256, 0, stream>>>(partials, k_lat, v_latT);

  stage2_attn<<<4096, 256, 0, stream>>>(qb, k_lat, v_latT, attn);
  gemm256<0, 0><<<gg, 512, 0, stream>>>(attn, Wb + 3 * 1048576, d_out, nullptr, nullptr, nullptr, 16384, 1024, 1024);
}

// Round 10
// 334.425 us; speedup vs baseline: 1.2528x; 1.2528x over previous
//
#include <hip/hip_runtime.h>
#include <hip/hip_bf16.h>
#include <stdint.h>

// MLAAttention on MI355X (gfx950).
// B=4 T=4096 D=1024 H=16 M=64 Dh=64. All inputs f32 (mask int32), output f32.
// R10: R9's 8-phase schedule with SPILL FIX: each fragment set is read and
//      fully consumed (32 MFMA) within one phase; stage/barrier/vmcnt placement
//      bit-identical to R9 (proven race-free; R9's regression was scratch
//      spill: VGPR 128-cap + 24 live frags -> WRITE_SIZE 66->92-116MB).

#define DEV static __device__ __forceinline__

using short8 = __attribute__((ext_vector_type(8))) short;
using f32x4  = __attribute__((ext_vector_type(4))) float;

#define ZERO4 (f32x4){0.f, 0.f, 0.f, 0.f}

DEV float bf2f(unsigned short u) {
  union { unsigned int i; float f; } c; c.i = ((unsigned int)u) << 16; return c.f;
}
DEV unsigned short f2bf(float f) {
  __hip_bfloat16 h = __float2bfloat16(f);
  unsigned short u; __builtin_memcpy(&u, &h, 2); return u;
}
DEV f32x4 mfma16(short8 a, short8 b, f32x4 c) {
  return __builtin_amdgcn_mfma_f32_16x16x32_bf16(a, b, c, 0, 0, 0);
}
#define GLOAD_LDS16(G, L) __builtin_amdgcn_global_load_lds( \
    (const __attribute__((address_space(1))) void*)(G),     \
    (__attribute__((address_space(3))) void*)(L), 16, 0, 0)

// ---------------------------------------------------------------- convert
__global__ void cvt_bf16(const float* __restrict__ src,
                         __hip_bfloat16* __restrict__ dst, int n) {
  int i = (blockIdx.x * blockDim.x + threadIdx.x) * 4;
  if (i >= n) return;
  const float4 v = *(const float4*)(src + i);
  ushort4 o;
  o.x = f2bf(v.x); o.y = f2bf(v.y); o.z = f2bf(v.z); o.w = f2bf(v.w);
  *(ushort4*)(dst + i) = o;
}

// ---------------------------------------------------------------- GEMM 256x256
// C[M,N] = A[M,K] @ Bt[N,K]^T, bf16 in, f32 acc. 8 waves (2M x 4N).
// 8-phase K-loop over 2 K-tiles/iter; XOR-swizzled LDS (R8): element (row,
// chunk c) at LDS (row, c ^ (row&7)); staged linear + pre-swizzled source.
// Phases: {ph0,ph1}=read buf0 half + stageB(k1) + 32 MFMA; {ph2,ph3}=stageA(k0+2);
// {ph4,ph5}=read buf1 half + stageB(k0+2) + 32 MFMA; {ph6,ph7}=stageA(k0+3).
// vmcnt(4) before ph0/ph4 (4 younger A-half loads in flight), vmcnt(0) last.
// MODE: 0 = f32 normal; 1 = bf16 normal; 2 = bf16 normal + bf16 transposed;
//       3 = bf16 transposed only.
// ROPE: rotary on acc before stores (pairs along n; t = m&4095, d = n&63).
// Transposed layout: Ct[((m>>12)*16 + (n>>6))*64 + (n&63)][t = m&4095]  (bf16)
template<int MODE, int ROPE>
__global__ __launch_bounds__(512, 2)
void gemm256(const __hip_bfloat16* __restrict__ A,
             const __hip_bfloat16* __restrict__ Bt,
             void* __restrict__ Cout, __hip_bfloat16* __restrict__ Ct,
             const float* __restrict__ cosT, const float* __restrict__ sinT,
             int M, int N, int K) {
  __shared__ __hip_bfloat16 As[2][256 * 64];
  __shared__ __hip_bfloat16 Bs[2][256 * 64];
  const int tid = threadIdx.x;
  const int w = tid >> 6, l = tid & 63;
  const int lr = l & 15, lg = l >> 4;
  const int rowA0 = blockIdx.x * 256;
  const int colB0 = blockIdx.y * 256;
  const int srow = w * 8 + (l >> 3);                 // staging row (row&7 = l>>3)
  const int skk  = (((l & 7) ^ (l >> 3)) * 8);       // pre-swizzled source k-chunk
  const __hip_bfloat16* Ab = A  + (size_t)(rowA0 + srow) * K + skk;
  const __hip_bfloat16* Bb = Bt + (size_t)(colB0 + srow) * K + skk;
  f32x4 acc[8][4];
#pragma unroll
  for (int i = 0; i < 8; ++i)
#pragma unroll
    for (int j = 0; j < 4; ++j) acc[i][j] = ZERO4;
  const int wr = (w >> 2) * 128;          // wave M-offset (0 or 128)
  const int wc = (w & 3) * 64;            // wave N-offset (0,64,128,192)
  const int NT = K >> 6;                  // 64-wide K-tiles (16 here)
  const int NI = NT >> 1;                 // iterations (2 K-tiles each)

#define STAGE_A(kt, h)                                                           \
  if ((kt) < NT) {                                                               \
    const size_t go = (size_t)((h) * 128) * K + (size_t)(kt) * 64;               \
    GLOAD_LDS16(Ab + go,                &As[(kt) & 1][((h) * 128 + w * 8) * 64]); \
    GLOAD_LDS16(Ab + go + (size_t)64 * K, &As[(kt) & 1][((h) * 128 + 64 + w * 8) * 64]); \
  }
#define STAGE_B(kt, h)                                                           \
  if ((kt) < NT) {                                                               \
    const size_t go = (size_t)((h) * 128) * K + (size_t)(kt) * 64;               \
    GLOAD_LDS16(Bb + go,                &Bs[(kt) & 1][((h) * 128 + w * 8) * 64]); \
    GLOAD_LDS16(Bb + go + (size_t)64 * K, &Bs[(kt) & 1][((h) * 128 + 64 + w * 8) * 64]); \
  }
  // read this wave's fragments for k-half s from buffer buf, consume fully.
#define READ_MM(buf, s)                                                          \
  {                                                                              \
    short8 fa[8], fb[4];                                                         \
    _Pragma("unroll")                                                            \
    for (int i = 0; i < 8; ++i)                                                  \
      fa[i] = *(const short8*)&As[buf][(wr + i * 16 + lr) * 64 +                 \
                                       ((((s) * 4 + lg) ^ (lr & 7)) * 8)];       \
    _Pragma("unroll")                                                            \
    for (int j = 0; j < 4; ++j)                                                  \
      fb[j] = *(const short8*)&Bs[buf][(wc + j * 16 + lr) * 64 +                 \
                                       ((((s) * 4 + lg) ^ (lr & 7)) * 8)];       \
    __builtin_amdgcn_s_setprio(1);                                               \
    _Pragma("unroll")                                                            \
    for (int i = 0; i < 8; ++i)                                                  \
      _Pragma("unroll")                                                          \
      for (int j = 0; j < 4; ++j)                                                \
        acc[i][j] = mfma16(fa[i], fb[j], acc[i][j]);                             \
    __builtin_amdgcn_s_setprio(0);                                               \
  }
#define PH_SYNC                                                                  \
  asm volatile("s_waitcnt lgkmcnt(0)" ::: "memory");                             \
  __builtin_amdgcn_s_barrier();                                                  \
  asm volatile("" ::: "memory");

  // prologue: kt0 fully, kt1 A-halves  (12 loads/thread)
  STAGE_A(0, 0); STAGE_A(0, 1); STAGE_B(0, 0); STAGE_B(0, 1);
  STAGE_A(1, 0); STAGE_A(1, 1);

  for (int it = 0; it < NI; ++it) {
    const int k0 = 2 * it, k1 = 2 * it + 1;
    // ph0: need k0 (buf0); 4 younger loads (k1 A-halves) stay in flight
    asm volatile("s_waitcnt vmcnt(4)" ::: "memory");
    PH_SYNC;
    STAGE_B(k1, 0);
    READ_MM(0, 0);
    // ph1
    PH_SYNC;
    STAGE_B(k1, 1);
    READ_MM(0, 1);
    // ph2  (buf0 reads done -> safe to restage buf0 with k0+2)
    PH_SYNC;
    STAGE_A(k0 + 2, 0);
    // ph3
    PH_SYNC;
    STAGE_A(k0 + 2, 1);
    // ph4: need k1 (buf1); younger loads = k0+2 A-halves (4), or 0 on last iter
    if (it + 1 < NI) { asm volatile("s_waitcnt vmcnt(4)" ::: "memory"); }
    else             { asm volatile("s_waitcnt vmcnt(0)" ::: "memory"); }
    PH_SYNC;
    STAGE_B(k0 + 2, 0);
    READ_MM(1, 0);
    // ph5
    PH_SYNC;
    STAGE_B(k0 + 2, 1);
    READ_MM(1, 1);
    // ph6  (buf1 reads done -> safe to restage buf1 with k0+3)
    PH_SYNC;
    STAGE_A(k0 + 3, 0);
    // ph7
    PH_SYNC;
    STAGE_A(k0 + 3, 1);
  }
#undef STAGE_A
#undef STAGE_B
#undef READ_MM
#undef PH_SYNC

  const int r0 = rowA0 + wr + lg * 4;     // global row (m) base, +i*16+r
  const int c0 = colB0 + wc + lr;         // global col (n), +j*16
  if (ROPE) {
#pragma unroll
    for (int i = 0; i < 8; ++i)
#pragma unroll
      for (int j = 0; j < 4; ++j)
#pragma unroll
        for (int r = 0; r < 4; ++r) {
          const int m = r0 + i * 16 + r;
          const int n = c0 + j * 16;
          const int t = m & 4095, d = n & 63;
          const float c = cosT[t * 64 + d];
          const float s = sinT[t * 64 + d];
          const float v = acc[i][j][r];
          const float other = __shfl_xor(v, 1, 64);
          acc[i][j][r] = v * c + ((n & 1) ? other : -other) * s;
        }
  }
  if (MODE <= 2) {
#pragma unroll
    for (int i = 0; i < 8; ++i)
#pragma unroll
      for (int j = 0; j < 4; ++j)
#pragma unroll
        for (int r = 0; r < 4; ++r) {
          const size_t idx = (size_t)(r0 + i * 16 + r) * N + (c0 + j * 16);
          if (MODE == 0) ((float*)Cout)[idx] = acc[i][j][r];
          else ((__hip_bfloat16*)Cout)[idx] = __float2bfloat16(acc[i][j][r]);
        }
  }
  if (MODE >= 2) {
#pragma unroll
    for (int i = 0; i < 8; ++i)
#pragma unroll
      for (int j = 0; j < 4; ++j) {
        const int m0 = r0 + i * 16;           // 4 contiguous t per lane
        const int n  = c0 + j * 16;
        const size_t row = (size_t)(((m0 >> 12) * 16 + (n >> 6)) * 64 + (n & 63));
        ushort4 pk;
        pk.x = f2bf(acc[i][j][0]); pk.y = f2bf(acc[i][j][1]);
        pk.z = f2bf(acc[i][j][2]); pk.w = f2bf(acc[i][j][3]);
        *(ushort4*)&Ct[row * 4096 + (m0 & 4095)] = pk;
      }
  }
}

// ---------------------------------------------------------------- stage1 logits (MFMA)
// S[bh][m][t] = 0.125 * sum_d latent[h][m][d]*K[b][t][h][d]  (bf16 store; -inf if masked)
// Fused online per-m (max,sum) partials: pmax/psum[(bh*8+chunk)*4 + wave][m].
__global__ __launch_bounds__(256)
void stage1_logits(const __hip_bfloat16* __restrict__ kmat,  // [B,T,H,64] (roped)
                   const float* __restrict__ latent,          // [H,64,64] f32
                   const int* __restrict__ mask,               // [B*T]
                   __hip_bfloat16* __restrict__ S,             // [bh][64][4096]
                   float* __restrict__ pmax, float* __restrict__ psum) {
  const int bh = blockIdx.x, chunk = blockIdx.y;
  const int b = bh >> 4, h = bh & 15;
  const int tid = threadIdx.x, w = tid >> 6, l = tid & 63;
  const int lr = l & 15, lg = l >> 4;
  short8 la[4][2];
#pragma unroll
  for (int n = 0; n < 4; ++n)
#pragma unroll
    for (int s = 0; s < 2; ++s) {
      const float* lp = &latent[((size_t)h * 64 + n * 16 + lr) * 64 + s * 32 + lg * 8];
      short8 f;
#pragma unroll
      for (int j = 0; j < 8; ++j) f[j] = (short)f2bf(lp[j]);
      la[n][s] = f;
    }
  float mx[16], sm[16];
#pragma unroll
  for (int i = 0; i < 16; ++i) { mx[i] = -3.0e38f; sm[i] = 0.f; }
  for (int tile = 0; tile < 8; ++tile) {
    const int t = chunk * 512 + tile * 64 + w * 16 + lr;
    const __hip_bfloat16* kp = &kmat[((size_t)(b * 4096 + t) * 16 + h) * 64 + lg * 8];
    const short8 kb0 = *(const short8*)kp;
    const short8 kb1 = *(const short8*)(kp + 32);
    const bool live = (mask[b * 4096 + t] != 0);
    f32x4 acc[4];
#pragma unroll
    for (int n = 0; n < 4; ++n) {
      acc[n] = ZERO4;
      acc[n] = mfma16(la[n][0], kb0, acc[n]);
      acc[n] = mfma16(la[n][1], kb1, acc[n]);
    }
#pragma unroll
    for (int n = 0; n < 4; ++n)
#pragma unroll
      for (int r = 0; r < 4; ++r) {
        const float v = acc[n][r] * 0.125f;
        const int m = n * 16 + lg * 4 + r;
        unsigned short sv = live ? f2bf(v) : (unsigned short)0xFF80;  // -inf
        ((unsigned short*)S)[((size_t)bh * 64 + m) * 4096 + t] = sv;
        if (live) {
          const int idx = n * 4 + r;
          const float nm = fmaxf(mx[idx], v);
          sm[idx] = sm[idx] * __expf(mx[idx] - nm) + __expf(v - nm);
          mx[idx] = nm;
        }
      }
  }
#pragma unroll
  for (int o = 1; o < 16; o <<= 1)
#pragma unroll
    for (int i = 0; i < 16; ++i) {
      const float omx = __shfl_xor(mx[i], o, 64);
      const float osm = __shfl_xor(sm[i], o, 64);
      const float nm = fmaxf(mx[i], omx);
      sm[i] = sm[i] * __expf(mx[i] - nm) + osm * __expf(omx - nm);
      mx[i] = nm;
    }
  if (lr == 0) {
    const size_t pb = ((size_t)(bh * 8 + chunk) * 4 + w) * 64;
#pragma unroll
    for (int n = 0; n < 4; ++n)
#pragma unroll
      for (int r = 0; r < 4; ++r) {
        const int m = n * 16 + lg * 4 + r;
        pmax[pb + m] = mx[n * 4 + r];
        psum[pb + m] = sm[n * 4 + r];
      }
  }
}

// combine 32 partials per (bh,m)
__global__ void stage1_reduce(const float* __restrict__ pmax,
                              const float* __restrict__ psum,
                              float* __restrict__ cmax, float* __restrict__ cinv) {
  const int i = blockIdx.x * 256 + threadIdx.x;
  if (i >= 4096) return;
  const int bh = i >> 6, m = i & 63;
  float mx = -3.0e38f;
#pragma unroll
  for (int c = 0; c < 32; ++c)
    mx = fmaxf(mx, pmax[((size_t)bh * 32 + c) * 64 + m]);
  float sm = 0.f;
#pragma unroll
  for (int c = 0; c < 32; ++c)
    sm += psum[((size_t)bh * 32 + c) * 64 + m] *
          __expf(pmax[((size_t)bh * 32 + c) * 64 + m] - mx);
  cmax[i] = mx;
  cinv[i] = 1.f / sm;
}

// ---------------------------------------------------------------- latent GEMM v5
// Direct-from-global register-fragment MFMA reduction with FUSED softmax-exp:
// fp = bf16(exp(S - cmax)*cinv) computed in-register from raw logits S.
// k_lat_part[m,d] = sum_t P[m,t]*kT[d,t]; v_latT_part[d,m] = sum_t vT[d,t]*P[m,t].
__global__ __launch_bounds__(256)
void latgemm5(const __hip_bfloat16* __restrict__ S,   // logits [bh][64][4096]
              const __hip_bfloat16* __restrict__ kT,
              const __hip_bfloat16* __restrict__ vT,
              const float* __restrict__ cmax, const float* __restrict__ cinv,
              float* __restrict__ partials) {   // [slice][bh][8192]
  const int bh = blockIdx.x;
  const int tid = threadIdx.x, w = tid >> 6, l = tid & 63;
  const int slice = blockIdx.y * 4 + w;
  const int lr = l & 15;            // frag row
  const int lk = (l >> 4) * 8;      // frag k-offset
  const size_t base = (size_t)bh * 64 * 4096;
  float cm[4], ci[4];
#pragma unroll
  for (int i = 0; i < 4; ++i) {
    cm[i] = cmax[bh * 64 + i * 16 + lr];
    ci[i] = cinv[bh * 64 + i * 16 + lr];
  }
  f32x4 ak[4][4], av[4][4];
#pragma unroll
  for (int i = 0; i < 4; ++i)
#pragma unroll
    for (int j = 0; j < 4; ++j) { ak[i][j] = ZERO4; av[i][j] = ZERO4; }
  for (int ks = 0; ks < 8; ++ks) {
    const int t = slice * 256 + ks * 32 + lk;
    short8 fp[4], fk[4], fv[4];
#pragma unroll
    for (int i = 0; i < 4; ++i) {
      const size_t ro = base + (size_t)(i * 16 + lr) * 4096 + t;
      const short8 sv = *(const short8*)&S[ro];
      short8 p;
#pragma unroll
      for (int j = 0; j < 8; ++j)
        p[j] = (short)f2bf(__expf(bf2f((unsigned short)sv[j]) - cm[i]) * ci[i]);
      fp[i] = p;
      fk[i] = *(const short8*)&kT[ro];
      fv[i] = *(const short8*)&vT[ro];
    }
#pragma unroll
    for (int i = 0; i < 4; ++i)
#pragma unroll
      for (int j = 0; j < 4; ++j) {
        ak[i][j] = mfma16(fp[i], fk[j], ak[i][j]);   // C[m][d]
        av[i][j] = mfma16(fv[i], fp[j], av[i][j]);   // C[d][m]
      }
  }
  float* pk = partials + ((size_t)(slice * 64 + bh)) * 8192;
#pragma unroll
  for (int i = 0; i < 4; ++i)
#pragma unroll
    for (int j = 0; j < 4; ++j)
#pragma unroll
      for (int r = 0; r < 4; ++r) {
        const int row = i * 16 + 4 * (l >> 4) + r;
        const int col = j * 16 + lr;
        pk[(size_t)row * 64 + col]        = ak[i][j][r];
        pk[4096 + (size_t)row * 64 + col] = av[i][j][r];
      }
}

// Sum 16 slice-partials -> bf16 k_lat [bh][m][d] and v_latT [bh][d][m]
__global__ void latreduce(const float* __restrict__ partials,
                          __hip_bfloat16* __restrict__ k_lat,
                          __hip_bfloat16* __restrict__ v_latT) {
  const int i = blockIdx.x * 256 + threadIdx.x;   // 524288
  const int bh = i >> 13, off = i & 8191;
  float sm = 0.f;
#pragma unroll
  for (int c = 0; c < 16; ++c)
    sm += partials[((size_t)(c * 64 + bh)) * 8192 + off];
  if (off < 4096) k_lat[(size_t)bh * 4096 + off] = __float2bfloat16(sm);
  else            v_latT[(size_t)bh * 4096 + (off - 4096)] = __float2bfloat16(sm);
}

// ---------------------------------------------------------------- stage2 fused
__global__ __launch_bounds__(256)
void stage2_attn(const __hip_bfloat16* __restrict__ q,
                 const __hip_bfloat16* __restrict__ k_lat,
                 const __hip_bfloat16* __restrict__ v_latT,
                 __hip_bfloat16* __restrict__ attn) {
  __shared__ unsigned short Pl[4][16][64];
  const int bid = blockIdx.x;
  const int bh = bid >> 6, tt = (bid & 63) * 64;
  const int b = bh >> 4, h = bh & 15;
  const int tid = threadIdx.x, w = tid >> 6, l = tid & 63;
  const size_t qoff = ((size_t)(b * 4096 + tt + w * 16 + (l & 15)) * 16 + h) * 64;
  const short8 a0 = *(const short8*)&q[qoff + (l >> 4) * 8];
  const short8 a1 = *(const short8*)&q[qoff + 32 + (l >> 4) * 8];
  f32x4 att[4];
#pragma unroll
  for (int n = 0; n < 4; ++n) att[n] = ZERO4;
#pragma unroll
  for (int n = 0; n < 4; ++n) {
    const __hip_bfloat16* kl = &k_lat[((size_t)bh * 64 + n * 16 + (l & 15)) * 64];
    const short8 b0 = *(const short8*)&kl[(l >> 4) * 8];
    const short8 b1 = *(const short8*)&kl[32 + (l >> 4) * 8];
    att[n] = mfma16(a0, b0, att[n]);
    att[n] = mfma16(a1, b1, att[n]);
  }
  float p[4][4];
#pragma unroll
  for (int r = 0; r < 4; ++r) {
    const float v0 = att[0][r] * 0.125f, v1 = att[1][r] * 0.125f;
    const float v2 = att[2][r] * 0.125f, v3 = att[3][r] * 0.125f;
    float mxv = fmaxf(fmaxf(v0, v1), fmaxf(v2, v3));
#pragma unroll
    for (int o = 1; o < 16; o <<= 1) mxv = fmaxf(mxv, __shfl_xor(mxv, o, 64));
    const float e0 = __expf(v0 - mxv), e1 = __expf(v1 - mxv);
    const float e2 = __expf(v2 - mxv), e3 = __expf(v3 - mxv);
    float sum = e0 + e1 + e2 + e3;
#pragma unroll
    for (int o = 1; o < 16; o <<= 1) sum += __shfl_xor(sum, o, 64);
    const float inv = 1.f / sum;
    p[0][r] = e0 * inv; p[1][r] = e1 * inv; p[2][r] = e2 * inv; p[3][r] = e3 * inv;
  }
#pragma unroll
  for (int n = 0; n < 4; ++n)
#pragma unroll
    for (int r = 0; r < 4; ++r) {
      const int row = 4 * (l >> 4) + r;
      const int col = n * 16 + (l & 15);
      Pl[w][row][col ^ ((row & 7) << 3)] = f2bf(p[n][r]);
    }
  __syncthreads();
  const int arow = l & 15;
  const short8 pa0 = *(const short8*)&Pl[w][arow][(((l >> 4) + 0) ^ (arow & 7)) * 8];
  const short8 pa1 = *(const short8*)&Pl[w][arow][(((l >> 4) + 4) ^ (arow & 7)) * 8];
  f32x4 ov[4];
#pragma unroll
  for (int n = 0; n < 4; ++n) ov[n] = ZERO4;
#pragma unroll
  for (int n = 0; n < 4; ++n) {
    const __hip_bfloat16* vt = &v_latT[((size_t)bh * 64 + n * 16 + (l & 15)) * 64];
    const short8 b0 = *(const short8*)&vt[(l >> 4) * 8];
    const short8 b1 = *(const short8*)&vt[32 + (l >> 4) * 8];
    ov[n] = mfma16(pa0, b0, ov[n]);
    ov[n] = mfma16(pa1, b1, ov[n]);
  }
#pragma unroll
  for (int n = 0; n < 4; ++n) {
    const int d = n * 16 + (l & 15);
#pragma unroll
    for (int r = 0; r < 4; ++r) {
      const int trow = tt + w * 16 + 4 * (l >> 4) + r;
      attn[((size_t)(b * 4096 + trow) * 16 + h) * 64 + d] = __float2bfloat16(ov[n][r]);
    }
  }
}

// ---------------------------------------------------------------- launch
extern "C" void kernel_launch(void* const* d_in, const int* in_sizes, int n_in,
                              void* d_out, int out_size, void* d_ws, size_t ws_size,
                              hipStream_t stream) {
  const float* x      = (const float*)d_in[0];
  const float* Wq     = (const float*)d_in[1];
  const float* Wk     = (const float*)d_in[2];
  const float* Wv     = (const float*)d_in[3];
  const float* Wo     = (const float*)d_in[4];
  const float* latent = (const float*)d_in[5];
  const float* cosT   = (const float*)d_in[6];
  const float* sinT   = (const float*)d_in[7];
  const int*   mask   = (const int*)d_in[8];

  char* ws = (char*)d_ws;
  __hip_bfloat16* xb = (__hip_bfloat16*)ws;                        // 33.5MB (reused as S)
  __hip_bfloat16* Wb = (__hip_bfloat16*)(ws + 33554432);           // 8.4MB
  __hip_bfloat16* qb = (__hip_bfloat16*)(ws + 41943040);           // 33.5MB (reused as attn)
  __hip_bfloat16* kb = (__hip_bfloat16*)(ws + 75497472);           // 33.5MB (reused as partials)
  __hip_bfloat16* kT = (__hip_bfloat16*)(ws + 109051904);          // 33.5MB [bh*64+d][t]
  __hip_bfloat16* vT = (__hip_bfloat16*)(ws + 142606336);          // 33.5MB
  char* tail = ws + 176160768;
  float* pmax = (float*)tail;                       // 131072 f
  float* psum = pmax + 131072;
  float* cmax = psum + 131072;                      // 4096 f
  float* cinv = cmax + 4096;
  __hip_bfloat16* k_lat  = (__hip_bfloat16*)(cinv + 4096);   // 262144 bf16
  __hip_bfloat16* v_latT = k_lat + 262144;

  __hip_bfloat16* S    = xb;                // xb dead after projection GEMMs
  __hip_bfloat16* attn = qb;                // qb dead after stage2 (in-place ok)
  float* partials = (float*)kb;             // kb dead after stage1_logits

  cvt_bf16<<<16384, 256, 0, stream>>>(x, xb, 16777216);
  cvt_bf16<<<1024, 256, 0, stream>>>(Wq, Wb + 0 * 1048576, 1048576);
  cvt_bf16<<<1024, 256, 0, stream>>>(Wk, Wb + 1 * 1048576, 1048576);
  cvt_bf16<<<1024, 256, 0, stream>>>(Wv, Wb + 2 * 1048576, 1048576);
  cvt_bf16<<<1024, 256, 0, stream>>>(Wo, Wb + 3 * 1048576, 1048576);

  dim3 gg(64, 4);
  gemm256<1, 1><<<gg, 512, 0, stream>>>(xb, Wb + 0 * 1048576, qb, nullptr, cosT, sinT, 16384, 1024, 1024);
  gemm256<2, 1><<<gg, 512, 0, stream>>>(xb, Wb + 1 * 1048576, kb, kT, cosT, sinT, 16384, 1024, 1024);
  gemm256<3, 0><<<gg, 512, 0, stream>>>(xb, Wb + 2 * 1048576, nullptr, vT, nullptr, nullptr, 16384, 1024, 1024);

  dim3 sg(64, 8);
  stage1_logits<<<sg, 256, 0, stream>>>(kb, latent, mask, S, pmax, psum);
  stage1_reduce<<<16, 256, 0, stream>>>(pmax, psum, cmax, cinv);

  dim3 lg(64, 4);
  latgemm5<<<lg, 256, 0, stream>>>(S, kT, vT, cmax, cinv, partials);
  latreduce<<<2048, 256, 0, stream>>>(partials, k_lat, v_latT);

  stage2_attn<<<4096, 256, 0, stream>>>(qb, k_lat, v_latT, attn);
  gemm256<0, 0><<<gg, 512, 0, stream>>>(attn, Wb + 3 * 1048576, d_out, nullptr, nullptr, nullptr, 16384, 1024, 1024);
}

// Round 11
// 312.805 us; speedup vs baseline: 1.3394x; 1.0691x over previous
//
#include <hip/hip_runtime.h>
#include <hip/hip_bf16.h>
#include <stdint.h>

// MLAAttention on MI355X (gfx950).
// B=4 T=4096 D=1024 H=16 M=64 Dh=64. All inputs f32 (mask int32), output f32.
// R11: gemm256 reverted to R8's proven 2-phase+swizzle (8-phase closed per R10);
//      tail cuts: single fused cvt launch, latgemm 8 slices (half partial
//      traffic), stage1_reduce folded into latgemm5.

#define DEV static __device__ __forceinline__

using short8 = __attribute__((ext_vector_type(8))) short;
using f32x4  = __attribute__((ext_vector_type(4))) float;

#define ZERO4 (f32x4){0.f, 0.f, 0.f, 0.f}

DEV float bf2f(unsigned short u) {
  union { unsigned int i; float f; } c; c.i = ((unsigned int)u) << 16; return c.f;
}
DEV unsigned short f2bf(float f) {
  __hip_bfloat16 h = __float2bfloat16(f);
  unsigned short u; __builtin_memcpy(&u, &h, 2); return u;
}
DEV f32x4 mfma16(short8 a, short8 b, f32x4 c) {
  return __builtin_amdgcn_mfma_f32_16x16x32_bf16(a, b, c, 0, 0, 0);
}
#define GLOAD_LDS16(G, L) __builtin_amdgcn_global_load_lds( \
    (const __attribute__((address_space(1))) void*)(G),     \
    (__attribute__((address_space(3))) void*)(L), 16, 0, 0)

// ---------------------------------------------------------------- fused convert
// blocks [0,16384): x -> xb ; [16384, 20480): W's -> Wb (1024 blocks each)
__global__ void cvt_all(const float* __restrict__ x,
                        const float* __restrict__ Wq, const float* __restrict__ Wk,
                        const float* __restrict__ Wv, const float* __restrict__ Wo,
                        __hip_bfloat16* __restrict__ xb,
                        __hip_bfloat16* __restrict__ Wb) {
  const int bid = blockIdx.x;
  const float* src;
  __hip_bfloat16* dst;
  int base;
  if (bid < 16384) {
    src = x; dst = xb; base = bid;
  } else {
    const int k = (bid - 16384) >> 10;
    src = (k == 0) ? Wq : (k == 1) ? Wk : (k == 2) ? Wv : Wo;
    dst = Wb + (size_t)k * 1048576;
    base = (bid - 16384) & 1023;
  }
  const int i = (base * 256 + threadIdx.x) * 4;
  const float4 v = *(const float4*)(src + i);
  ushort4 o;
  o.x = f2bf(v.x); o.y = f2bf(v.y); o.z = f2bf(v.z); o.w = f2bf(v.w);
  *(ushort4*)(dst + i) = o;
}

// ---------------------------------------------------------------- GEMM 256x256
// C[M,N] = A[M,K] @ Bt[N,K]^T, bf16 in, f32 acc. 8 waves (2M x 4N), 2-phase
// double-buffered K-loop, counted vmcnt. LDS layout XOR-swizzled:
// element (row, chunk c of 8 bf16) lives at LDS (row, c ^ (row&7)).
// Staged via linear gload_lds dest + pre-swizzled global source (staging row&7
// = l>>3); read back with chunk ^ (lr&7) (fragment row&7 = lr&7).
// MODE: 0 = f32 normal; 1 = bf16 normal; 2 = bf16 normal + bf16 transposed;
//       3 = bf16 transposed only.
// ROPE: apply rotary (pairs along n; t = m&4095, d = n&63) to acc before stores.
// Transposed layout: Ct[((m>>12)*16 + (n>>6))*64 + (n&63)][t = m&4095]  (bf16)
template<int MODE, int ROPE>
__global__ __launch_bounds__(512, 2)
void gemm256(const __hip_bfloat16* __restrict__ A,
             const __hip_bfloat16* __restrict__ Bt,
             void* __restrict__ Cout, __hip_bfloat16* __restrict__ Ct,
             const float* __restrict__ cosT, const float* __restrict__ sinT,
             int M, int N, int K) {
  __shared__ __hip_bfloat16 As[2][256 * 64];
  __shared__ __hip_bfloat16 Bs[2][256 * 64];
  const int tid = threadIdx.x;
  const int w = tid >> 6, l = tid & 63;
  const int lr = l & 15, lg = l >> 4;
  const int rowA0 = blockIdx.x * 256;
  const int colB0 = blockIdx.y * 256;
  const int srow = w * 8 + (l >> 3);                 // staging row (row&7 = l>>3)
  const int skk  = (((l & 7) ^ (l >> 3)) * 8);       // pre-swizzled source k-chunk
  const __hip_bfloat16* Ab = A  + (size_t)(rowA0 + srow) * K + skk;
  const __hip_bfloat16* Bb = Bt + (size_t)(colB0 + srow) * K + skk;
  f32x4 acc[8][4];
#pragma unroll
  for (int i = 0; i < 8; ++i)
#pragma unroll
    for (int j = 0; j < 4; ++j) acc[i][j] = ZERO4;
  const int wr = (w >> 2) * 128;          // wave M-offset (0 or 128)
  const int wc = (w & 3) * 64;            // wave N-offset (0,64,128,192)
  const int NT = K >> 6;

#define G_STAGE(kt, buf)                                                          \
  {                                                                               \
    const int k0s = (kt) * 64;                                                    \
    _Pragma("unroll")                                                             \
    for (int i = 0; i < 4; ++i) {                                                 \
      GLOAD_LDS16(Ab + (size_t)(i * 64) * K + k0s, &As[buf][i * 4096 + w * 512]); \
      GLOAD_LDS16(Bb + (size_t)(i * 64) * K + k0s, &Bs[buf][i * 4096 + w * 512]); \
    }                                                                             \
  }

  G_STAGE(0, 0);
  for (int kt = 0; kt < NT; ++kt) {
    const int cur = kt & 1;
    if (kt + 1 < NT) {
      G_STAGE(kt + 1, cur ^ 1);                         // prefetch other slot
      asm volatile("s_waitcnt vmcnt(8)" ::: "memory");  // own stage(kt) landed
    } else {
      asm volatile("s_waitcnt vmcnt(0)" ::: "memory");
    }
    __builtin_amdgcn_s_barrier();                       // all waves' stage(kt) visible
    __builtin_amdgcn_s_setprio(1);
#pragma unroll
    for (int s = 0; s < 2; ++s) {
      short8 fa[8], fb[4];
#pragma unroll
      for (int i = 0; i < 8; ++i)
        fa[i] = *(const short8*)&As[cur][(wr + i * 16 + lr) * 64 +
                                         (((s * 4 + lg) ^ (lr & 7)) * 8)];
#pragma unroll
      for (int j = 0; j < 4; ++j)
        fb[j] = *(const short8*)&Bs[cur][(wc + j * 16 + lr) * 64 +
                                         (((s * 4 + lg) ^ (lr & 7)) * 8)];
#pragma unroll
      for (int i = 0; i < 8; ++i)
#pragma unroll
        for (int j = 0; j < 4; ++j)
          acc[i][j] = mfma16(fa[i], fb[j], acc[i][j]);
    }
    __builtin_amdgcn_s_setprio(0);
    __builtin_amdgcn_s_barrier();                       // slot reads done before restage
  }
#undef G_STAGE

  const int r0 = rowA0 + wr + lg * 4;     // global row (m) base, +i*16+r
  const int c0 = colB0 + wc + lr;         // global col (n), +j*16
  if (ROPE) {
#pragma unroll
    for (int i = 0; i < 8; ++i)
#pragma unroll
      for (int j = 0; j < 4; ++j)
#pragma unroll
        for (int r = 0; r < 4; ++r) {
          const int m = r0 + i * 16 + r;
          const int n = c0 + j * 16;
          const int t = m & 4095, d = n & 63;
          const float c = cosT[t * 64 + d];
          const float s = sinT[t * 64 + d];
          const float v = acc[i][j][r];
          const float other = __shfl_xor(v, 1, 64);
          acc[i][j][r] = v * c + ((n & 1) ? other : -other) * s;
        }
  }
  if (MODE <= 2) {
#pragma unroll
    for (int i = 0; i < 8; ++i)
#pragma unroll
      for (int j = 0; j < 4; ++j)
#pragma unroll
        for (int r = 0; r < 4; ++r) {
          const size_t idx = (size_t)(r0 + i * 16 + r) * N + (c0 + j * 16);
          if (MODE == 0) ((float*)Cout)[idx] = acc[i][j][r];
          else ((__hip_bfloat16*)Cout)[idx] = __float2bfloat16(acc[i][j][r]);
        }
  }
  if (MODE >= 2) {
#pragma unroll
    for (int i = 0; i < 8; ++i)
#pragma unroll
      for (int j = 0; j < 4; ++j) {
        const int m0 = r0 + i * 16;           // 4 contiguous t per lane
        const int n  = c0 + j * 16;
        const size_t row = (size_t)(((m0 >> 12) * 16 + (n >> 6)) * 64 + (n & 63));
        ushort4 pk;
        pk.x = f2bf(acc[i][j][0]); pk.y = f2bf(acc[i][j][1]);
        pk.z = f2bf(acc[i][j][2]); pk.w = f2bf(acc[i][j][3]);
        *(ushort4*)&Ct[row * 4096 + (m0 & 4095)] = pk;
      }
  }
}

// ---------------------------------------------------------------- stage1 logits (MFMA)
// S[bh][m][t] = 0.125 * sum_d latent[h][m][d]*K[b][t][h][d]  (bf16 store; -inf if masked)
// Fused online per-m (max,sum) partials: pmax/psum[(bh*8+chunk)*4 + wave][m].
__global__ __launch_bounds__(256)
void stage1_logits(const __hip_bfloat16* __restrict__ kmat,  // [B,T,H,64] (roped)
                   const float* __restrict__ latent,          // [H,64,64] f32
                   const int* __restrict__ mask,               // [B*T]
                   __hip_bfloat16* __restrict__ S,             // [bh][64][4096]
                   float* __restrict__ pmax, float* __restrict__ psum) {
  const int bh = blockIdx.x, chunk = blockIdx.y;
  const int b = bh >> 4, h = bh & 15;
  const int tid = threadIdx.x, w = tid >> 6, l = tid & 63;
  const int lr = l & 15, lg = l >> 4;
  short8 la[4][2];
#pragma unroll
  for (int n = 0; n < 4; ++n)
#pragma unroll
    for (int s = 0; s < 2; ++s) {
      const float* lp = &latent[((size_t)h * 64 + n * 16 + lr) * 64 + s * 32 + lg * 8];
      short8 f;
#pragma unroll
      for (int j = 0; j < 8; ++j) f[j] = (short)f2bf(lp[j]);
      la[n][s] = f;
    }
  float mx[16], sm[16];
#pragma unroll
  for (int i = 0; i < 16; ++i) { mx[i] = -3.0e38f; sm[i] = 0.f; }
  for (int tile = 0; tile < 8; ++tile) {
    const int t = chunk * 512 + tile * 64 + w * 16 + lr;
    const __hip_bfloat16* kp = &kmat[((size_t)(b * 4096 + t) * 16 + h) * 64 + lg * 8];
    const short8 kb0 = *(const short8*)kp;
    const short8 kb1 = *(const short8*)(kp + 32);
    const bool live = (mask[b * 4096 + t] != 0);
    f32x4 acc[4];
#pragma unroll
    for (int n = 0; n < 4; ++n) {
      acc[n] = ZERO4;
      acc[n] = mfma16(la[n][0], kb0, acc[n]);
      acc[n] = mfma16(la[n][1], kb1, acc[n]);
    }
#pragma unroll
    for (int n = 0; n < 4; ++n)
#pragma unroll
      for (int r = 0; r < 4; ++r) {
        const float v = acc[n][r] * 0.125f;
        const int m = n * 16 + lg * 4 + r;
        unsigned short sv = live ? f2bf(v) : (unsigned short)0xFF80;  // -inf
        ((unsigned short*)S)[((size_t)bh * 64 + m) * 4096 + t] = sv;
        if (live) {
          const int idx = n * 4 + r;
          const float nm = fmaxf(mx[idx], v);
          sm[idx] = sm[idx] * __expf(mx[idx] - nm) + __expf(v - nm);
          mx[idx] = nm;
        }
      }
  }
#pragma unroll
  for (int o = 1; o < 16; o <<= 1)
#pragma unroll
    for (int i = 0; i < 16; ++i) {
      const float omx = __shfl_xor(mx[i], o, 64);
      const float osm = __shfl_xor(sm[i], o, 64);
      const float nm = fmaxf(mx[i], omx);
      sm[i] = sm[i] * __expf(mx[i] - nm) + osm * __expf(omx - nm);
      mx[i] = nm;
    }
  if (lr == 0) {
    const size_t pb = ((size_t)(bh * 8 + chunk) * 4 + w) * 64;
#pragma unroll
    for (int n = 0; n < 4; ++n)
#pragma unroll
      for (int r = 0; r < 4; ++r) {
        const int m = n * 16 + lg * 4 + r;
        pmax[pb + m] = mx[n * 4 + r];
        psum[pb + m] = sm[n * 4 + r];
      }
  }
}

// ---------------------------------------------------------------- latent GEMM v6
// Direct-from-global register-fragment MFMA reduction, fused softmax-exp AND
// fused cmax/cinv computation (32-chunk combine done per block in LDS).
// 8 slices of 512 t; grid (bh=64, 2); wave w covers slice blockIdx.y*4+w.
__global__ __launch_bounds__(256)
void latgemm6(const __hip_bfloat16* __restrict__ S,   // logits [bh][64][4096]
              const __hip_bfloat16* __restrict__ kT,
              const __hip_bfloat16* __restrict__ vT,
              const float* __restrict__ pmax, const float* __restrict__ psum,
              float* __restrict__ partials) {   // [slice(8)][bh][8192]
  __shared__ float scm[64], sci[64];
  const int bh = blockIdx.x;
  const int tid = threadIdx.x, w = tid >> 6, l = tid & 63;
  const int slice = blockIdx.y * 4 + w;
  const int lr = l & 15;            // frag row
  const int lk = (l >> 4) * 8;      // frag k-offset
  const size_t base = (size_t)bh * 64 * 4096;
  if (tid < 64) {
    float mxv = -3.0e38f;
#pragma unroll
    for (int c = 0; c < 32; ++c)
      mxv = fmaxf(mxv, pmax[((size_t)bh * 32 + c) * 64 + tid]);
    float smv = 0.f;
#pragma unroll
    for (int c = 0; c < 32; ++c)
      smv += psum[((size_t)bh * 32 + c) * 64 + tid] *
             __expf(pmax[((size_t)bh * 32 + c) * 64 + tid] - mxv);
    scm[tid] = mxv;
    sci[tid] = 1.f / smv;
  }
  __syncthreads();
  float cm[4], ci[4];
#pragma unroll
  for (int i = 0; i < 4; ++i) {
    cm[i] = scm[i * 16 + lr];
    ci[i] = sci[i * 16 + lr];
  }
  f32x4 ak[4][4], av[4][4];
#pragma unroll
  for (int i = 0; i < 4; ++i)
#pragma unroll
    for (int j = 0; j < 4; ++j) { ak[i][j] = ZERO4; av[i][j] = ZERO4; }
  for (int ks = 0; ks < 16; ++ks) {
    const int t = slice * 512 + ks * 32 + lk;
    short8 fp[4], fk[4], fv[4];
#pragma unroll
    for (int i = 0; i < 4; ++i) {
      const size_t ro = base + (size_t)(i * 16 + lr) * 4096 + t;
      const short8 sv = *(const short8*)&S[ro];
      short8 p;
#pragma unroll
      for (int j = 0; j < 8; ++j)
        p[j] = (short)f2bf(__expf(bf2f((unsigned short)sv[j]) - cm[i]) * ci[i]);
      fp[i] = p;
      fk[i] = *(const short8*)&kT[ro];
      fv[i] = *(const short8*)&vT[ro];
    }
#pragma unroll
    for (int i = 0; i < 4; ++i)
#pragma unroll
      for (int j = 0; j < 4; ++j) {
        ak[i][j] = mfma16(fp[i], fk[j], ak[i][j]);   // C[m][d]
        av[i][j] = mfma16(fv[i], fp[j], av[i][j]);   // C[d][m]
      }
  }
  float* pk = partials + ((size_t)(slice * 64 + bh)) * 8192;
#pragma unroll
  for (int i = 0; i < 4; ++i)
#pragma unroll
    for (int j = 0; j < 4; ++j)
#pragma unroll
      for (int r = 0; r < 4; ++r) {
        const int row = i * 16 + 4 * (l >> 4) + r;
        const int col = j * 16 + lr;
        pk[(size_t)row * 64 + col]        = ak[i][j][r];
        pk[4096 + (size_t)row * 64 + col] = av[i][j][r];
      }
}

// Sum 8 slice-partials -> bf16 k_lat [bh][m][d] and v_latT [bh][d][m]
__global__ void latreduce(const float* __restrict__ partials,
                          __hip_bfloat16* __restrict__ k_lat,
                          __hip_bfloat16* __restrict__ v_latT) {
  const int i = blockIdx.x * 256 + threadIdx.x;   // 524288
  const int bh = i >> 13, off = i & 8191;
  float sm = 0.f;
#pragma unroll
  for (int c = 0; c < 8; ++c)
    sm += partials[((size_t)(c * 64 + bh)) * 8192 + off];
  if (off < 4096) k_lat[(size_t)bh * 4096 + off] = __float2bfloat16(sm);
  else            v_latT[(size_t)bh * 4096 + (off - 4096)] = __float2bfloat16(sm);
}

// ---------------------------------------------------------------- stage2 fused
__global__ __launch_bounds__(256)
void stage2_attn(const __hip_bfloat16* __restrict__ q,
                 const __hip_bfloat16* __restrict__ k_lat,
                 const __hip_bfloat16* __restrict__ v_latT,
                 __hip_bfloat16* __restrict__ attn) {
  __shared__ unsigned short Pl[4][16][64];
  const int bid = blockIdx.x;
  const int bh = bid >> 6, tt = (bid & 63) * 64;
  const int b = bh >> 4, h = bh & 15;
  const int tid = threadIdx.x, w = tid >> 6, l = tid & 63;
  const size_t qoff = ((size_t)(b * 4096 + tt + w * 16 + (l & 15)) * 16 + h) * 64;
  const short8 a0 = *(const short8*)&q[qoff + (l >> 4) * 8];
  const short8 a1 = *(const short8*)&q[qoff + 32 + (l >> 4) * 8];
  f32x4 att[4];
#pragma unroll
  for (int n = 0; n < 4; ++n) att[n] = ZERO4;
#pragma unroll
  for (int n = 0; n < 4; ++n) {
    const __hip_bfloat16* kl = &k_lat[((size_t)bh * 64 + n * 16 + (l & 15)) * 64];
    const short8 b0 = *(const short8*)&kl[(l >> 4) * 8];
    const short8 b1 = *(const short8*)&kl[32 + (l >> 4) * 8];
    att[n] = mfma16(a0, b0, att[n]);
    att[n] = mfma16(a1, b1, att[n]);
  }
  float p[4][4];
#pragma unroll
  for (int r = 0; r < 4; ++r) {
    const float v0 = att[0][r] * 0.125f, v1 = att[1][r] * 0.125f;
    const float v2 = att[2][r] * 0.125f, v3 = att[3][r] * 0.125f;
    float mxv = fmaxf(fmaxf(v0, v1), fmaxf(v2, v3));
#pragma unroll
    for (int o = 1; o < 16; o <<= 1) mxv = fmaxf(mxv, __shfl_xor(mxv, o, 64));
    const float e0 = __expf(v0 - mxv), e1 = __expf(v1 - mxv);
    const float e2 = __expf(v2 - mxv), e3 = __expf(v3 - mxv);
    float sum = e0 + e1 + e2 + e3;
#pragma unroll
    for (int o = 1; o < 16; o <<= 1) sum += __shfl_xor(sum, o, 64);
    const float inv = 1.f / sum;
    p[0][r] = e0 * inv; p[1][r] = e1 * inv; p[2][r] = e2 * inv; p[3][r] = e3 * inv;
  }
#pragma unroll
  for (int n = 0; n < 4; ++n)
#pragma unroll
    for (int r = 0; r < 4; ++r) {
      const int row = 4 * (l >> 4) + r;
      const int col = n * 16 + (l & 15);
      Pl[w][row][col ^ ((row & 7) << 3)] = f2bf(p[n][r]);
    }
  __syncthreads();
  const int arow = l & 15;
  const short8 pa0 = *(const short8*)&Pl[w][arow][(((l >> 4) + 0) ^ (arow & 7)) * 8];
  const short8 pa1 = *(const short8*)&Pl[w][arow][(((l >> 4) + 4) ^ (arow & 7)) * 8];
  f32x4 ov[4];
#pragma unroll
  for (int n = 0; n < 4; ++n) ov[n] = ZERO4;
#pragma unroll
  for (int n = 0; n < 4; ++n) {
    const __hip_bfloat16* vt = &v_latT[((size_t)bh * 64 + n * 16 + (l & 15)) * 64];
    const short8 b0 = *(const short8*)&vt[(l >> 4) * 8];
    const short8 b1 = *(const short8*)&vt[32 + (l >> 4) * 8];
    ov[n] = mfma16(pa0, b0, ov[n]);
    ov[n] = mfma16(pa1, b1, ov[n]);
  }
#pragma unroll
  for (int n = 0; n < 4; ++n) {
    const int d = n * 16 + (l & 15);
#pragma unroll
    for (int r = 0; r < 4; ++r) {
      const int trow = tt + w * 16 + 4 * (l >> 4) + r;
      attn[((size_t)(b * 4096 + trow) * 16 + h) * 64 + d] = __float2bfloat16(ov[n][r]);
    }
  }
}

// ---------------------------------------------------------------- launch
extern "C" void kernel_launch(void* const* d_in, const int* in_sizes, int n_in,
                              void* d_out, int out_size, void* d_ws, size_t ws_size,
                              hipStream_t stream) {
  const float* x      = (const float*)d_in[0];
  const float* Wq     = (const float*)d_in[1];
  const float* Wk     = (const float*)d_in[2];
  const float* Wv     = (const float*)d_in[3];
  const float* Wo     = (const float*)d_in[4];
  const float* latent = (const float*)d_in[5];
  const float* cosT   = (const float*)d_in[6];
  const float* sinT   = (const float*)d_in[7];
  const int*   mask   = (const int*)d_in[8];

  char* ws = (char*)d_ws;
  __hip_bfloat16* xb = (__hip_bfloat16*)ws;                        // 33.5MB (reused as S)
  __hip_bfloat16* Wb = (__hip_bfloat16*)(ws + 33554432);           // 8.4MB
  __hip_bfloat16* qb = (__hip_bfloat16*)(ws + 41943040);           // 33.5MB (reused as attn)
  __hip_bfloat16* kb = (__hip_bfloat16*)(ws + 75497472);           // 33.5MB (reused as partials)
  __hip_bfloat16* kT = (__hip_bfloat16*)(ws + 109051904);          // 33.5MB [bh*64+d][t]
  __hip_bfloat16* vT = (__hip_bfloat16*)(ws + 142606336);          // 33.5MB
  char* tail = ws + 176160768;
  float* pmax = (float*)tail;                       // 131072 f
  float* psum = pmax + 131072;
  __hip_bfloat16* k_lat  = (__hip_bfloat16*)(psum + 131072);   // 262144 bf16
  __hip_bfloat16* v_latT = k_lat + 262144;

  __hip_bfloat16* S    = xb;                // xb dead after projection GEMMs
  __hip_bfloat16* attn = qb;                // qb dead after stage2 (in-place ok)
  float* partials = (float*)kb;             // kb dead after stage1_logits; 8*64*8192*4B = 16.8MB

  cvt_all<<<20480, 256, 0, stream>>>(x, Wq, Wk, Wv, Wo, xb, Wb);

  dim3 gg(64, 4);
  gemm256<1, 1><<<gg, 512, 0, stream>>>(xb, Wb + 0 * 1048576, qb, nullptr, cosT, sinT, 16384, 1024, 1024);
  gemm256<2, 1><<<gg, 512, 0, stream>>>(xb, Wb + 1 * 1048576, kb, kT, cosT, sinT, 16384, 1024, 1024);
  gemm256<3, 0><<<gg, 512, 0, stream>>>(xb, Wb + 2 * 1048576, nullptr, vT, nullptr, nullptr, 16384, 1024, 1024);

  dim3 sg(64, 8);
  stage1_logits<<<sg, 256, 0, stream>>>(kb, latent, mask, S, pmax, psum);

  dim3 lg(64, 2);
  latgemm6<<<lg, 256, 0, stream>>>(S, kT, vT, pmax, psum, partials);
  latreduce<<<2048, 256, 0, stream>>>(partials, k_lat, v_latT);

  stage2_attn<<<4096, 256, 0, stream>>>(qb, k_lat, v_latT, attn);
  gemm256<0, 0><<<gg, 512, 0, stream>>>(attn, Wb + 3 * 1048576, d_out, nullptr, nullptr, nullptr, 16384, 1024, 1024);
}